// Round 2
// baseline (42195.071 us; speedup 1.0000x reference)
//
#include <hip/hip_runtime.h>
#include <math.h>

#define PLANE 884736          // 96*96*96
#define NPLANES 64            // B*C = 2*32

// ---------------------------------------------------------------------------
// Prep: expert MLPs (mod[4][27], biasK[4][32]), scaled cluster centers,
// weight transposes [o][c][s] -> [s][c][o] for SGPR-friendly access.
// ---------------------------------------------------------------------------
__global__ void prep_kernel(
    const float* __restrict__ cc,
    const float* __restrict__ proj_w,
    const float* __restrict__ base_w,
    const float* __restrict__ w1, const float* __restrict__ b1,
    const float* __restrict__ w2, const float* __restrict__ b2,
    const float* __restrict__ w3, const float* __restrict__ b3,
    const float* __restrict__ g1, const float* __restrict__ gb1,
    const float* __restrict__ g2, const float* __restrict__ gb2,
    float* __restrict__ wT1, float* __restrict__ wT2,
    float* __restrict__ modv, float* __restrict__ biasK,
    float* __restrict__ ccs)
{
    __shared__ float ccl[4][32];
    __shared__ float h1s[4][128];
    __shared__ float h2s[4][128];
    __shared__ float bhs[4][64];
    const int tid = threadIdx.x;

    if (tid < 128) {
        float v = cc[tid];
        ccl[tid >> 5][tid & 31] = v;
        ccs[tid] = v * 0.17677669529663687f;   // 1/sqrt(32)
    }
    __syncthreads();

    // h1 = relu(cc @ w1^T + b1)  [4][128]
    for (int r = 0; r < 2; ++r) {
        int id = tid + r * 256;
        int k = id >> 7, i = id & 127;
        float s = b1[i];
        for (int c = 0; c < 32; ++c) s = fmaf(ccl[k][c], w1[i * 32 + c], s);
        h1s[k][i] = fmaxf(s, 0.f);
    }
    __syncthreads();

    // h2 = relu(h1 @ w2^T + b2)  [4][128]
    for (int r = 0; r < 2; ++r) {
        int id = tid + r * 256;
        int k = id >> 7, i = id & 127;
        float s = b2[i];
        for (int j = 0; j < 128; ++j) s = fmaf(h1s[k][j], w2[i * 128 + j], s);
        h2s[k][i] = fmaxf(s, 0.f);
    }
    __syncthreads();

    // mod = sigmoid(h2 @ w3^T + b3)  [4][27]
    if (tid < 108) {
        int k = tid / 27, t = tid - k * 27;
        float s = b3[t];
        for (int j = 0; j < 128; ++j) s = fmaf(h2s[k][j], w3[t * 128 + j], s);
        modv[tid] = 1.f / (1.f + expf(-s));
    }

    // bias path: bh = relu(cc @ g1^T + gb1)  [4][64]
    {
        int k = tid >> 6, i = tid & 63;
        float s = gb1[i];
        for (int c = 0; c < 32; ++c) s = fmaf(ccl[k][c], g1[i * 32 + c], s);
        bhs[k][i] = fmaxf(s, 0.f);
    }
    __syncthreads();

    // biasK = bh @ g2^T + gb2  [4][32]
    if (tid < 128) {
        int k = tid >> 5, o = tid & 31;
        float s = gb2[o];
        for (int i = 0; i < 64; ++i) s = fmaf(bhs[k][i], g2[o * 64 + i], s);
        biasK[tid] = s;
    }

    // transpose weights: src [o][c][s] flat -> dst [(s*32 + c)*32 + o]
    for (int idx = tid; idx < 27648; idx += 256) {
        int o = idx / 864;
        int rem = idx - o * 864;
        int c = rem / 27;
        int s = rem - c * 27;
        int dst = (s * 32 + c) * 32 + o;
        wT1[dst] = proj_w[idx];
        wT2[dst] = base_w[idx];
    }
}

// ---------------------------------------------------------------------------
// Direct 3^3 conv, 32ch -> 32ch. Tile 16x8x8 voxels (1024), 4 voxels/thread
// along x. Input staged in 8-channel chunks: LDS [8][10][10][20] = 62.5 KB
// -> 2 blocks/CU. Each thread: 128 accumulators (32 o x 4 vox). Weights via
// uniform scalar loads; 128 FMAs per 32-float weight row (4x amortization).
// Epilogue computes per-block instance-norm partial sums (fused reduction).
// MODE 0: plain conv. MODE 1: per-voxel effmod-modulated conv + mixed bias.
// ---------------------------------------------------------------------------
template <int MODE>
__global__ __launch_bounds__(256, 2) void conv_kernel(
    const float* __restrict__ in,      // [B*32][PLANE]
    const float* __restrict__ wT,      // [27][32][32]  (s, c, o)
    const float* __restrict__ cw,      // [B*4][PLANE]    (MODE 1)
    const float* __restrict__ modv,    // [4][27]         (MODE 1)
    const float* __restrict__ biasK,   // [4][32]         (MODE 1)
    float* __restrict__ out,           // [B*32][PLANE]
    float* __restrict__ partials)      // [B*864][32][2]
{
    __shared__ float lx[16000];        // [8][10z][10y][20x]

    const int b = blockIdx.y;
    const int bx = blockIdx.x;
    const int tx = bx % 6;
    const int ty = (bx / 6) % 12;
    const int tz = bx / 72;
    const int x0 = tx * 16, y0 = ty * 8, z0 = tz * 8;
    const int tid = threadIdx.x;
    const int vx0 = (tid & 3) * 4;
    const int vy = (tid >> 2) & 7;
    const int vz = tid >> 5;

    const size_t gvox = ((size_t)(z0 + vz) * 96 + (y0 + vy)) * 96 + (x0 + vx0);
    const float* inb = in + (size_t)b * 32 * PLANE;

    float acc[128];
#pragma unroll
    for (int i = 0; i < 128; ++i) acc[i] = 0.f;

    float cwv[4][4];                   // [k][v]
    if (MODE == 1) {
#pragma unroll
        for (int k = 0; k < 4; ++k) {
            float4 t = *(const float4*)(cw + ((size_t)(b * 4 + k)) * PLANE + gvox);
            cwv[k][0] = t.x; cwv[k][1] = t.y; cwv[k][2] = t.z; cwv[k][3] = t.w;
        }
    }

#pragma unroll 1
    for (int chunk = 0; chunk < 4; ++chunk) {
        if (chunk) __syncthreads();    // WAR on lx
        const float* cin = inb + (size_t)chunk * 8 * PLANE;
        for (int idx = tid; idx < 14400; idx += 256) {
            int cc8 = idx / 1800; int r = idx - cc8 * 1800;
            int hz = r / 180; r -= hz * 180;
            int hy = r / 18; int hx = r - hy * 18;
            int gz = z0 + hz - 1, gy = y0 + hy - 1, gx = x0 + hx - 1;
            float v = 0.f;
            if ((unsigned)gz < 96u && (unsigned)gy < 96u && (unsigned)gx < 96u)
                v = cin[(size_t)cc8 * PLANE + (size_t)(gz * 96 + gy) * 96 + gx];
            lx[((cc8 * 10 + hz) * 10 + hy) * 20 + hx] = v;
        }
        __syncthreads();

#pragma unroll 1
        for (int dzy = 0; dzy < 9; ++dzy) {
            const int dz = dzy / 3, dy = dzy - dz * 3;
            const float* lbase = &lx[((vz + dz) * 10 + (vy + dy)) * 20 + vx0];

            float em[3][4];            // [dx][v], invariant over c
            if (MODE == 1) {
#pragma unroll
                for (int dx = 0; dx < 3; ++dx) {
                    const int s = dzy * 3 + dx;
#pragma unroll
                    for (int v = 0; v < 4; ++v) {
                        float e = cwv[0][v] * modv[s];
                        e = fmaf(cwv[1][v], modv[27 + s], e);
                        e = fmaf(cwv[2][v], modv[54 + s], e);
                        e = fmaf(cwv[3][v], modv[81 + s], e);
                        em[dx][v] = e;
                    }
                }
            }

#pragma unroll 2
            for (int c = 0; c < 8; ++c) {
                const float* lb = lbase + c * 2000;
                float4 wa = *(const float4*)lb;
                float2 wb = *(const float2*)(lb + 4);
                const float w6[6] = {wa.x, wa.y, wa.z, wa.w, wb.x, wb.y};
                const float* wrow = wT + ((size_t)dzy * 3 * 32 + (chunk * 8 + c)) * 32;
#pragma unroll
                for (int dx = 0; dx < 3; ++dx) {
                    const float* wr = wrow + dx * 1024;   // uniform -> s_load
                    float xs0, xs1, xs2, xs3;
                    if (MODE == 1) {
                        xs0 = w6[dx + 0] * em[dx][0];
                        xs1 = w6[dx + 1] * em[dx][1];
                        xs2 = w6[dx + 2] * em[dx][2];
                        xs3 = w6[dx + 3] * em[dx][3];
                    } else {
                        xs0 = w6[dx + 0]; xs1 = w6[dx + 1];
                        xs2 = w6[dx + 2]; xs3 = w6[dx + 3];
                    }
#pragma unroll
                    for (int o = 0; o < 32; ++o) {
                        const float w = wr[o];
                        acc[o * 4 + 0] = fmaf(w, xs0, acc[o * 4 + 0]);
                        acc[o * 4 + 1] = fmaf(w, xs1, acc[o * 4 + 1]);
                        acc[o * 4 + 2] = fmaf(w, xs2, acc[o * 4 + 2]);
                        acc[o * 4 + 3] = fmaf(w, xs3, acc[o * 4 + 3]);
                    }
                }
            }
        }
    }

    // bias mix (MODE 1) — must precede stats and stores
    if (MODE == 1) {
#pragma unroll
        for (int o = 0; o < 32; ++o) {
#pragma unroll
            for (int v = 0; v < 4; ++v) {
                float bo = cwv[0][v] * biasK[o];
                bo = fmaf(cwv[1][v], biasK[32 + o], bo);
                bo = fmaf(cwv[2][v], biasK[64 + o], bo);
                bo = fmaf(cwv[3][v], biasK[96 + o], bo);
                acc[o * 4 + v] += bo;
            }
        }
    }

    // global stores (coalesced float4 per o)
    float* outb = out + (size_t)b * 32 * PLANE + gvox;
#pragma unroll
    for (int o = 0; o < 32; ++o) {
        *(float4*)(outb + (size_t)o * PLANE) =
            make_float4(acc[o * 4], acc[o * 4 + 1], acc[o * 4 + 2], acc[o * 4 + 3]);
    }

    // fused instance-norm partial sums: per-block [32][2]
    __syncthreads();                    // everyone done reading lx
    float* sred = lx;                   // [4 waves][32][2]
#pragma unroll 1
    for (int o = 0; o < 32; ++o) {
        float s = acc[o * 4] + acc[o * 4 + 1] + acc[o * 4 + 2] + acc[o * 4 + 3];
        float q = acc[o * 4] * acc[o * 4];
        q = fmaf(acc[o * 4 + 1], acc[o * 4 + 1], q);
        q = fmaf(acc[o * 4 + 2], acc[o * 4 + 2], q);
        q = fmaf(acc[o * 4 + 3], acc[o * 4 + 3], q);
#pragma unroll
        for (int off = 32; off > 0; off >>= 1) {
            s += __shfl_down(s, off);
            q += __shfl_down(q, off);
        }
        if ((tid & 63) == 0) {
            sred[((tid >> 6) * 32 + o) * 2]     = s;
            sred[((tid >> 6) * 32 + o) * 2 + 1] = q;
        }
    }
    __syncthreads();
    if (tid < 64) {
        const int o = tid & 31, st = tid >> 5;
        float v = sred[o * 2 + st] + sred[(32 + o) * 2 + st]
                + sred[(64 + o) * 2 + st] + sred[(96 + o) * 2 + st];
        partials[(((size_t)b * 864 + bx) * 32 + o) * 2 + st] = v;
    }
}

// ---------------------------------------------------------------------------
// Final stats: reduce 864 per-block partials per (b,c) plane -> mean, rstd.
// ---------------------------------------------------------------------------
__global__ __launch_bounds__(256) void reduce_stats(
    const float* __restrict__ partials, float* __restrict__ stats)
{
    const int p = blockIdx.x;          // 0..63
    const int b = p >> 5, o = p & 31;
    const int tid = threadIdx.x;
    float s = 0.f, q = 0.f;
    for (int t = tid; t < 864; t += 256) {
        const float* e = partials + (((size_t)b * 864 + t) * 32 + o) * 2;
        s += e[0]; q += e[1];
    }
#pragma unroll
    for (int off = 32; off > 0; off >>= 1) {
        s += __shfl_down(s, off);
        q += __shfl_down(q, off);
    }
    __shared__ float ls[4][2];
    if ((tid & 63) == 0) { ls[tid >> 6][0] = s; ls[tid >> 6][1] = q; }
    __syncthreads();
    if (tid == 0) {
        s = ls[0][0] + ls[1][0] + ls[2][0] + ls[3][0];
        q = ls[0][1] + ls[1][1] + ls[2][1] + ls[3][1];
        float mean = s / (float)PLANE;
        float var  = q / (float)PLANE - mean * mean;
        var = fmaxf(var, 0.f);
        stats[p * 2]     = mean;
        stats[p * 2 + 1] = rsqrtf(var + 1e-5f);
    }
}

// ---------------------------------------------------------------------------
// Fused InstanceNorm + LeakyReLU + cluster softmax. Reads raw conv1 (d_out),
// writes xp (ws) and cw (ws).
// ---------------------------------------------------------------------------
__global__ __launch_bounds__(256) void norm_softmax_kernel(
    const float* __restrict__ y1,      // [B*32][PLANE] raw conv1
    const float* __restrict__ stats,   // [64][2]
    const float* __restrict__ ccs,     // [4][32] scaled centers
    float* __restrict__ xp,            // [B*32][PLANE]
    float* __restrict__ cwout)         // [B*4][PLANE]
{
    const int b = blockIdx.y;
    const size_t p = (size_t)blockIdx.x * 256 + threadIdx.x;
    const float* yb = y1 + (size_t)b * 32 * PLANE + p;
    float* xpb = xp + (size_t)b * 32 * PLANE + p;

    float s0 = 0.f, s1 = 0.f, s2 = 0.f, s3 = 0.f;
#pragma unroll
    for (int c = 0; c < 32; ++c) {
        float v = yb[(size_t)c * PLANE];
        const float m = stats[(b * 32 + c) * 2];
        const float r = stats[(b * 32 + c) * 2 + 1];
        float xn = (v - m) * r;
        xn = xn >= 0.f ? xn : 0.1f * xn;
        xpb[(size_t)c * PLANE] = xn;
        s0 = fmaf(xn, ccs[c],      s0);
        s1 = fmaf(xn, ccs[32 + c], s1);
        s2 = fmaf(xn, ccs[64 + c], s2);
        s3 = fmaf(xn, ccs[96 + c], s3);
    }
    float mx = fmaxf(fmaxf(s0, s1), fmaxf(s2, s3));
    float e0 = expf(s0 - mx), e1 = expf(s1 - mx), e2 = expf(s2 - mx), e3 = expf(s3 - mx);
    float inv = 1.f / (e0 + e1 + e2 + e3);
    float* cwb = cwout + (size_t)b * 4 * PLANE + p;
    cwb[0]          = e0 * inv;
    cwb[PLANE]      = e1 * inv;
    cwb[2 * PLANE]  = e2 * inv;
    cwb[3 * PLANE]  = e3 * inv;
}

// ---------------------------------------------------------------------------
// Final: out = lrelu(inorm(out_raw)) + x   (in place on d_out)
// ---------------------------------------------------------------------------
__global__ __launch_bounds__(256) void finalize_kernel(
    float* __restrict__ out,
    const float* __restrict__ x,
    const float* __restrict__ stats)
{
    const int plane = blockIdx.y;      // 0..63
    const float m = stats[plane * 2];
    const float r = stats[plane * 2 + 1];
    const size_t base = (size_t)plane * PLANE + (size_t)blockIdx.x * 1024 + threadIdx.x * 4;
    float4 v  = *(const float4*)(out + base);
    float4 xi = *(const float4*)(x + base);
    float4 o;
    float t;
    t = (v.x - m) * r; t = t >= 0.f ? t : 0.1f * t; o.x = t + xi.x;
    t = (v.y - m) * r; t = t >= 0.f ? t : 0.1f * t; o.y = t + xi.y;
    t = (v.z - m) * r; t = t >= 0.f ? t : 0.1f * t; o.z = t + xi.z;
    t = (v.w - m) * r; t = t >= 0.f ? t : 0.1f * t; o.w = t + xi.w;
    *(float4*)(out + base) = o;
}

// ---------------------------------------------------------------------------
extern "C" void kernel_launch(void* const* d_in, const int* in_sizes, int n_in,
                              void* d_out, int out_size, void* d_ws, size_t ws_size,
                              hipStream_t stream)
{
    const float* x      = (const float*)d_in[0];
    const float* cc     = (const float*)d_in[1];
    const float* proj_w = (const float*)d_in[2];
    const float* base_w = (const float*)d_in[3];
    const float* wm_w1  = (const float*)d_in[4];
    const float* wm_b1  = (const float*)d_in[5];
    const float* wm_w2  = (const float*)d_in[6];
    const float* wm_b2  = (const float*)d_in[7];
    const float* wm_w3  = (const float*)d_in[8];
    const float* wm_b3  = (const float*)d_in[9];
    const float* bg_w1  = (const float*)d_in[10];
    const float* bg_b1  = (const float*)d_in[11];
    const float* bg_w2  = (const float*)d_in[12];
    const float* bg_b2  = (const float*)d_in[13];
    float* out = (float*)d_out;

    // workspace carve (floats)
    float* xp       = (float*)d_ws;             // 2*32*PLANE = 56,623,104
    float* cw       = xp + (size_t)56623104;    // 2*4*PLANE  =  7,077,888
    float* wT1      = cw + (size_t)7077888;     // 27,648
    float* wT2      = wT1 + 27648;              // 27,648
    float* modv     = wT2 + 27648;              // 128 (108 used)
    float* biasK    = modv + 128;               // 128
    float* ccs      = biasK + 128;              // 128
    float* partials = ccs + 128;                // 2*864*32*2 = 110,592
    float* stats1   = partials + 110592;        // 128
    float* stats2   = stats1 + 128;             // 128

    // 1. prep (tiny)
    prep_kernel<<<1, 256, 0, stream>>>(cc, proj_w, base_w,
                                       wm_w1, wm_b1, wm_w2, wm_b2, wm_w3, wm_b3,
                                       bg_w1, bg_b1, bg_w2, bg_b2,
                                       wT1, wT2, modv, biasK, ccs);

    const dim3 cgrid(864, 2);    // 6x * 12y * 12z tiles, B=2

    // 2. conv1 -> d_out (raw) + fused norm partials
    conv_kernel<0><<<cgrid, 256, 0, stream>>>(x, wT1, nullptr, nullptr, nullptr,
                                              out, partials);
    reduce_stats<<<64, 256, 0, stream>>>(partials, stats1);

    // 3. norm + lrelu + softmax -> xp, cw
    norm_softmax_kernel<<<dim3(3456, 2), 256, 0, stream>>>(out, stats1, ccs, xp, cw);

    // 4. modulated conv2 -> d_out (raw) + fused norm partials
    conv_kernel<1><<<cgrid, 256, 0, stream>>>(xp, wT2, cw, modv, biasK,
                                              out, partials);
    reduce_stats<<<64, 256, 0, stream>>>(partials, stats2);

    // 5. final norm + lrelu + residual (in place)
    finalize_kernel<<<dim3(864, NPLANES), 256, 0, stream>>>(out, x, stats2);
}